// Round 4
// baseline (237.382 us; speedup 1.0000x reference)
//
#include <hip/hip_runtime.h>

// PolicyEncoder: out[n,:] = bias + w_state0[obs0[n]] + w_state1[obs1[n]]
//                          + w_act0[act0[n]] + w_act1[act1[n]]
// N = 262144 rows, D = 128 fp32. Memory-bound gather+sum.
// R3: output stores fully bypass L2/L3 (global_store_dwordx4 sc0 sc1 nt via
//     inline asm) so the 131 MB streaming write stops evicting the 78 MB of
//     tables from Infinity Cache. Plus 4 rows/thread (16 outstanding gathers).

#define PE_N 262144
#define PE_D 128
#define ROWS_PER_BLOCK 32   // 8 row-slots * 4 rows per thread

typedef float v4f __attribute__((ext_vector_type(4)));

__device__ __forceinline__ void store_bypass(v4f val, const v4f* addr) {
    // sc0 sc1: bypass L2 (system-scope write);  nt: no-allocate in MALL/L3.
    asm volatile("global_store_dwordx4 %0, %1, off sc0 sc1 nt"
                 :: "v"(addr), "v"(val) : "memory");
}

__global__ __launch_bounds__(256) void PolicyEncoder_79044578116211_kernel(
    const int* __restrict__ obs0, const int* __restrict__ obs1,
    const int* __restrict__ act0, const int* __restrict__ act1,
    const float* __restrict__ w_state0, const float* __restrict__ w_state1,
    const float* __restrict__ w_act0, const float* __restrict__ w_act1,
    const float* __restrict__ bias, float* __restrict__ out)
{
    const int t    = threadIdx.x;
    const int slot = t >> 5;          // 0..7
    const int lane = t & 31;          // float4 index within a row

    const int base = blockIdx.x * ROWS_PER_BLOCK + slot;

    int rows[4];
    rows[0] = base;
    rows[1] = base + 8;
    rows[2] = base + 16;
    rows[3] = base + 24;

    // Gather indices for 4 rows (broadcast within each 32-lane row group).
    int i0[4], i1[4], a0[4], a1[4];
#pragma unroll
    for (int r = 0; r < 4; ++r) {
        i0[r] = obs0[rows[r]];
        i1[r] = obs1[rows[r]];
        a0[r] = act0[rows[r]];
        a1[r] = act1[rows[r]];
    }

    const v4f* b4 = (const v4f*)bias;
    v4f xb = b4[lane];

    // 16 independent gathers in flight.
    v4f g0[4], g1[4], g2[4], g3[4];
#pragma unroll
    for (int r = 0; r < 4; ++r) {
        g0[r] = ((const v4f*)(w_state0 + (size_t)i0[r] * PE_D))[lane];
        g1[r] = ((const v4f*)(w_state1 + (size_t)i1[r] * PE_D))[lane];
        g2[r] = ((const v4f*)(w_act0   + (size_t)a0[r] * PE_D))[lane];
        g3[r] = ((const v4f*)(w_act1   + (size_t)a1[r] * PE_D))[lane];
    }

#pragma unroll
    for (int r = 0; r < 4; ++r) {
        v4f acc = xb + g0[r] + g1[r] + g2[r] + g3[r];
        store_bypass(acc, (const v4f*)(out + (size_t)rows[r] * PE_D) + lane);
    }
}

extern "C" void kernel_launch(void* const* d_in, const int* in_sizes, int n_in,
                              void* d_out, int out_size, void* d_ws, size_t ws_size,
                              hipStream_t stream) {
    const int*   obs0     = (const int*)  d_in[0];
    const int*   obs1     = (const int*)  d_in[1];
    const int*   act0     = (const int*)  d_in[2];
    const int*   act1     = (const int*)  d_in[3];
    const float* w_state0 = (const float*)d_in[4];
    const float* w_state1 = (const float*)d_in[5];
    const float* w_act0   = (const float*)d_in[6];
    const float* w_act1   = (const float*)d_in[7];
    const float* bias     = (const float*)d_in[8];
    float*       out      = (float*)d_out;

    const int grid = PE_N / ROWS_PER_BLOCK;  // 8192 blocks
    PolicyEncoder_79044578116211_kernel<<<grid, 256, 0, stream>>>(
        obs0, obs1, act0, act1, w_state0, w_state1, w_act0, w_act1, bias, out);
}